// Round 1
// baseline (283.483 us; speedup 1.0000x reference)
//
#include <hip/hip_runtime.h>
#include <cstdint>

#define SRC_LEN 2048
#define BSZ     64
#define CTX     512
#define ATT     256
#define BM      128
#define BK      32
#define NCHUNK  16
#define LOG2E   1.4426950408889634f

typedef unsigned short u16;
typedef unsigned int   u32;
typedef unsigned char  u8;
typedef __attribute__((ext_vector_type(8))) short bf16x8;
typedef __attribute__((ext_vector_type(4))) float f32x4;

__device__ inline u16 f2bf(float f) {
    u32 u = __float_as_uint(f);
    u32 r = (u + 0x7FFFu + ((u >> 16) & 1u)) >> 16;
    return (u16)r;
}
__device__ inline float bf2f(u16 h) { return __uint_as_float((u32)h << 16); }

__device__ inline float fast_exp2(float x) {
#if __has_builtin(__builtin_amdgcn_exp2f)
    return __builtin_amdgcn_exp2f(x);
#else
    return exp2f(x);
#endif
}
__device__ inline float fast_rcp(float x) {
#if __has_builtin(__builtin_amdgcn_rcpf)
    return __builtin_amdgcn_rcpf(x);
#else
    return 1.0f / x;
#endif
}
__device__ inline float fast_tanh(float x) {
    float e = fast_exp2(x * (2.0f * LOG2E));
    return 1.0f - 2.0f * fast_rcp(e + 1.0f);
}

// ---------------------------------------------------------------------------
// Kernel 1: prep — decoder projection, W_enc hi/lo bf16 split, mask dtype probe
// grid 64 (one per batch b), 256 threads
// ---------------------------------------------------------------------------
__global__ __launch_bounds__(256) void prep_kernel(
    const float* __restrict__ dec_state, const float* __restrict__ W_dec,
    const float* __restrict__ W_enc, const u8* __restrict__ mask_bytes,
    float* __restrict__ decproj, u16* __restrict__ wh, u16* __restrict__ wl,
    int* __restrict__ flag)
{
    const int b = blockIdx.x, t = threadIdx.x;
    __shared__ float ds[CTX];
    for (int k = t; k < CTX; k += 256) ds[k] = dec_state[b * CTX + k];
    __syncthreads();

    // decproj[b][t] = dot(dec_state[b,:], W_dec[t,:])
    const float* wrow = W_dec + t * CTX;
    float acc = 0.f;
#pragma unroll 4
    for (int k = 0; k < CTX; k += 4) {
        float4 w4 = *reinterpret_cast<const float4*>(wrow + k);
        acc += w4.x * ds[k] + w4.y * ds[k + 1] + w4.z * ds[k + 2] + w4.w * ds[k + 3];
    }
    decproj[b * ATT + t] = acc;

    // split W_enc (256x512 fp32) into hi/lo bf16; 8 elements per thread
    const int base = (b * 256 + t) * 8;
#pragma unroll
    for (int i = 0; i < 8; i += 4) {
        float4 f = *reinterpret_cast<const float4*>(W_enc + base + i);
        float fv[4] = {f.x, f.y, f.z, f.w};
#pragma unroll
        for (int j = 0; j < 4; ++j) {
            u16 h = f2bf(fv[j]);
            wh[base + i + j] = h;
            wl[base + i + j] = f2bf(fv[j] - bf2f(h));
        }
    }

    // mask dtype probe: int32 0/1 data has zero bytes at every idx%4!=0.
    // reading 131072 bytes is in-bounds for both uint8 and int32 layouts.
    const int gid = b * 256 + t;
    int bad = 0;
#pragma unroll
    for (int i = 0; i < 8; ++i) {
        int idx = gid * 8 + i;
        if ((idx & 3) != 0 && mask_bytes[idx] != 0) bad = 1;
    }
    if (bad) atomicOr(flag, 1);
}

// ---------------------------------------------------------------------------
// Kernel 2: score — split-bf16 MFMA GEMM (enc proj) + tanh + v-dot epilogue
// grid 1024 (BM=128 rows each, row = s*64+b), 256 threads = 4 waves
// ---------------------------------------------------------------------------
__global__ __launch_bounds__(256) void score_kernel(
    const float* __restrict__ hids, const u16* __restrict__ wh,
    const u16* __restrict__ wl, const float* __restrict__ decproj,
    const float* __restrict__ b_enc, const float* __restrict__ vvec,
    const u8* __restrict__ maskB, const int* __restrict__ maskI,
    const int* __restrict__ flag, float* __restrict__ scoresT)
{
    __shared__ u16 lAh[BM * BK], lAl[BM * BK];
    __shared__ u16 lBh[ATT * BK], lBl[ATT * BK];
    __shared__ float spart[4][BM];

    const int tid  = threadIdx.x;
    const int wave = tid >> 6, lane = tid & 63;
    const int ln15 = lane & 15, lg = lane >> 4;
    const int rowBase = blockIdx.x * BM;

    f32x4 acc[8][4];
#pragma unroll
    for (int m = 0; m < 8; ++m)
#pragma unroll
        for (int n = 0; n < 4; ++n) acc[m][n] = (f32x4){0.f, 0.f, 0.f, 0.f};

    const int arow = tid >> 1;          // 0..127
    const int ahalf = tid & 1;          // 16-col half
    const int c0 = ahalf * 2;

#pragma unroll 1
    for (int kt = 0; kt < CTX; kt += BK) {
        // ---- stage A: 128 rows x 32 cols fp32 -> hi/lo bf16, swizzled ----
        {
            const float* src = hids + (size_t)(rowBase + arow) * CTX + kt + ahalf * 16;
            float fv[16];
#pragma unroll
            for (int q = 0; q < 4; ++q) {
                float4 f4 = reinterpret_cast<const float4*>(src)[q];
                fv[q * 4 + 0] = f4.x; fv[q * 4 + 1] = f4.y;
                fv[q * 4 + 2] = f4.z; fv[q * 4 + 3] = f4.w;
            }
            u32 hp[8], lp[8];
#pragma unroll
            for (int j = 0; j < 8; ++j) {
                u16 h0 = f2bf(fv[2 * j]), h1 = f2bf(fv[2 * j + 1]);
                u16 l0 = f2bf(fv[2 * j] - bf2f(h0));
                u16 l1 = f2bf(fv[2 * j + 1] - bf2f(h1));
                hp[j] = (u32)h0 | ((u32)h1 << 16);
                lp[j] = (u32)l0 | ((u32)l1 << 16);
            }
            const int rs = arow & 3;
            uint4 u;
            u.x = hp[0]; u.y = hp[1]; u.z = hp[2]; u.w = hp[3];
            *reinterpret_cast<uint4*>(&lAh[arow * BK + ((c0 ^ rs) * 8)]) = u;
            u.x = hp[4]; u.y = hp[5]; u.z = hp[6]; u.w = hp[7];
            *reinterpret_cast<uint4*>(&lAh[arow * BK + (((c0 + 1) ^ rs) * 8)]) = u;
            u.x = lp[0]; u.y = lp[1]; u.z = lp[2]; u.w = lp[3];
            *reinterpret_cast<uint4*>(&lAl[arow * BK + ((c0 ^ rs) * 8)]) = u;
            u.x = lp[4]; u.y = lp[5]; u.z = lp[6]; u.w = lp[7];
            *reinterpret_cast<uint4*>(&lAl[arow * BK + (((c0 + 1) ^ rs) * 8)]) = u;
        }
        // ---- stage B: 256 rows x 32 cols of wh/wl (bf16), swizzled ----
#pragma unroll
        for (int p = 0; p < 2; ++p) {
            const int row = p * 128 + (tid >> 1);
            const int rs = row & 3;
            const u16* sh = wh + row * CTX + kt + ahalf * 16;
            const u16* sl = wl + row * CTX + kt + ahalf * 16;
            uint4 q0 = reinterpret_cast<const uint4*>(sh)[0];
            uint4 q1 = reinterpret_cast<const uint4*>(sh)[1];
            *reinterpret_cast<uint4*>(&lBh[row * BK + ((c0 ^ rs) * 8)]) = q0;
            *reinterpret_cast<uint4*>(&lBh[row * BK + (((c0 + 1) ^ rs) * 8)]) = q1;
            q0 = reinterpret_cast<const uint4*>(sl)[0];
            q1 = reinterpret_cast<const uint4*>(sl)[1];
            *reinterpret_cast<uint4*>(&lBl[row * BK + ((c0 ^ rs) * 8)]) = q0;
            *reinterpret_cast<uint4*>(&lBl[row * BK + (((c0 + 1) ^ rs) * 8)]) = q1;
        }
        __syncthreads();

        // ---- MFMA: 3-term split product ----
        bf16x8 bHf[4], bLf[4];
#pragma unroll
        for (int n = 0; n < 4; ++n) {
            const int row = wave * 64 + n * 16 + ln15;
            const int off = row * BK + ((lg ^ (row & 3)) * 8);
            bHf[n] = *reinterpret_cast<const bf16x8*>(&lBh[off]);
            bLf[n] = *reinterpret_cast<const bf16x8*>(&lBl[off]);
        }
#pragma unroll
        for (int m = 0; m < 8; ++m) {
            const int row = m * 16 + ln15;
            const int off = row * BK + ((lg ^ (row & 3)) * 8);
            bf16x8 aH = *reinterpret_cast<const bf16x8*>(&lAh[off]);
            bf16x8 aL = *reinterpret_cast<const bf16x8*>(&lAl[off]);
#pragma unroll
            for (int n = 0; n < 4; ++n) {
                acc[m][n] = __builtin_amdgcn_mfma_f32_16x16x32_bf16(aH, bHf[n], acc[m][n], 0, 0, 0);
                acc[m][n] = __builtin_amdgcn_mfma_f32_16x16x32_bf16(aH, bLf[n], acc[m][n], 0, 0, 0);
                acc[m][n] = __builtin_amdgcn_mfma_f32_16x16x32_bf16(aL, bHf[n], acc[m][n], 0, 0, 0);
            }
        }
        __syncthreads();
    }

    // ---- epilogue: x = enc + b_enc + decproj; score += tanh(x)*v ----
    float bE[4], vE[4];
#pragma unroll
    for (int n = 0; n < 4; ++n) {
        const int a = wave * 64 + n * 16 + ln15;
        bE[n] = b_enc[a];
        vE[n] = vvec[a];
    }
#pragma unroll
    for (int m = 0; m < 8; ++m) {
#pragma unroll
        for (int j = 0; j < 4; ++j) {
            const int rl = m * 16 + lg * 4 + j;
            const int b  = rl & 63;
            const float* dp = decproj + b * ATT + wave * 64 + ln15;
            float partial = 0.f;
#pragma unroll
            for (int n = 0; n < 4; ++n) {
                float x = acc[m][n][j] + bE[n] + dp[n * 16];
                partial += fast_tanh(x) * vE[n];
            }
            partial += __shfl_xor(partial, 1);
            partial += __shfl_xor(partial, 2);
            partial += __shfl_xor(partial, 4);
            partial += __shfl_xor(partial, 8);
            if (ln15 == 0) spart[wave][rl] = partial;
        }
    }
    __syncthreads();

    if (tid < BM) {
        const int rl = tid;
        const int s = (rowBase + rl) >> 6;
        const int b = rl & 63;
        float sc = spart[0][rl] + spart[1][rl] + spart[2][rl] + spart[3][rl];
        const int isByte = *flag;
        int mv;
        if (isByte) mv = (int)maskB[s * BSZ + b];
        else        mv = maskI[s * BSZ + b];
        scoresT[b * SRC_LEN + s] = (mv != 0) ? -1e30f : sc;
    }
}

// ---------------------------------------------------------------------------
// Kernel 3: softmax over s per batch column b. grid 64, 256 threads.
// writes wT[b][s] (fp32 ws) and normalized output [s][b]
// ---------------------------------------------------------------------------
__global__ __launch_bounds__(256) void softmax_kernel(
    const float* __restrict__ scoresT, float* __restrict__ wT,
    float* __restrict__ outNorm)
{
    const int b = blockIdx.x, t = threadIdx.x;
    const int wv = t >> 6, ln = t & 63;
    __shared__ float red[8];

    float v[8];
    float m = -1e30f;
#pragma unroll
    for (int i = 0; i < 8; ++i) {
        v[i] = scoresT[b * SRC_LEN + i * 256 + t];
        m = fmaxf(m, v[i]);
    }
#pragma unroll
    for (int o = 1; o < 64; o <<= 1) m = fmaxf(m, __shfl_xor(m, o));
    if (ln == 0) red[wv] = m;
    __syncthreads();
    m = fmaxf(fmaxf(red[0], red[1]), fmaxf(red[2], red[3]));

    float e[8];
    float ssum = 0.f;
#pragma unroll
    for (int i = 0; i < 8; ++i) {
        e[i] = fast_exp2((v[i] - m) * LOG2E);
        ssum += e[i];
    }
#pragma unroll
    for (int o = 1; o < 64; o <<= 1) ssum += __shfl_xor(ssum, o);
    if (ln == 0) red[4 + wv] = ssum;
    __syncthreads();
    ssum = red[4] + red[5] + red[6] + red[7];

    const float inv = 1.0f / ssum;
#pragma unroll
    for (int i = 0; i < 8; ++i) {
        const float w = e[i] * inv;
        const int s = i * 256 + t;
        wT[b * SRC_LEN + s] = w;
        outNorm[s * BSZ + b] = w;
    }
}

// ---------------------------------------------------------------------------
// Kernel 4: context partial sums. grid (64 b, 16 s-chunks), 128 threads.
// ---------------------------------------------------------------------------
__global__ __launch_bounds__(128) void context_partial(
    const float* __restrict__ hids, const float* __restrict__ wT,
    float* __restrict__ partials)
{
    const int b = blockIdx.x, chunk = blockIdx.y, t = threadIdx.x;
    float4 acc = {0.f, 0.f, 0.f, 0.f};
    const int s0 = chunk * (SRC_LEN / NCHUNK);
#pragma unroll 4
    for (int s = s0; s < s0 + (SRC_LEN / NCHUNK); ++s) {
        const float w = wT[b * SRC_LEN + s];
        if (w != 0.0f) {   // masked tail: exactly zero -> skip load (wave-uniform)
            float4 h = reinterpret_cast<const float4*>(hids + (size_t)(s * BSZ + b) * CTX)[t];
            acc.x += w * h.x; acc.y += w * h.y; acc.z += w * h.z; acc.w += w * h.w;
        }
    }
    reinterpret_cast<float4*>(partials + (size_t)(chunk * BSZ + b) * CTX)[t] = acc;
}

// ---------------------------------------------------------------------------
// Kernel 5: reduce partials -> context output. grid 64, 128 threads.
// ---------------------------------------------------------------------------
__global__ __launch_bounds__(128) void context_reduce(
    const float* __restrict__ partials, float* __restrict__ ctx)
{
    const int b = blockIdx.x, t = threadIdx.x;
    float4 acc = {0.f, 0.f, 0.f, 0.f};
#pragma unroll
    for (int c = 0; c < NCHUNK; ++c) {
        float4 p = reinterpret_cast<const float4*>(partials + (size_t)(c * BSZ + b) * CTX)[t];
        acc.x += p.x; acc.y += p.y; acc.z += p.z; acc.w += p.w;
    }
    reinterpret_cast<float4*>(ctx + (size_t)b * CTX)[t] = acc;
}

// ---------------------------------------------------------------------------
extern "C" void kernel_launch(void* const* d_in, const int* in_sizes, int n_in,
                              void* d_out, int out_size, void* d_ws, size_t ws_size,
                              hipStream_t stream)
{
    const float* dec_state = (const float*)d_in[0];
    const float* hids      = (const float*)d_in[1];
    const void*  mask_raw  = d_in[2];
    const float* W_enc     = (const float*)d_in[3];
    const float* b_enc     = (const float*)d_in[4];
    const float* W_dec     = (const float*)d_in[5];
    const float* vvec      = (const float*)d_in[6];

    float* out_ctx  = (float*)d_out;                 // [64][512]
    float* out_norm = out_ctx + BSZ * CTX;           // [2048][64]

    char* ws = (char*)d_ws;
    float* decproj  = (float*)(ws);                             //  64*256*4   = 65536
    u16*   wh       = (u16*)(ws + 65536);                       // 256*512*2   = 262144
    u16*   wl       = (u16*)(ws + 65536 + 262144);              // 262144
    float* scoresT  = (float*)(ws + 589824);                    // 64*2048*4   = 524288
    float* wT       = (float*)(ws + 1114112);                   // 524288
    float* partials = (float*)(ws + 1638400);                   // 16*64*512*4 = 2097152
    int*   flag     = (int*)(ws + 3735552);

    hipMemsetAsync(flag, 0, 4, stream);

    prep_kernel<<<64, 256, 0, stream>>>(dec_state, W_dec, W_enc,
                                        (const u8*)mask_raw, decproj, wh, wl, flag);

    score_kernel<<<(SRC_LEN * BSZ) / BM, 256, 0, stream>>>(
        hids, wh, wl, decproj, b_enc, vvec,
        (const u8*)mask_raw, (const int*)mask_raw, flag, scoresT);

    softmax_kernel<<<BSZ, 256, 0, stream>>>(scoresT, wT, out_norm);

    context_partial<<<dim3(BSZ, NCHUNK), 128, 0, stream>>>(hids, wT, partials);

    context_reduce<<<BSZ, 128, 0, stream>>>(partials, out_ctx);
}

// Round 2
// 234.226 us; speedup vs baseline: 1.2103x; 1.2103x over previous
//
#include <hip/hip_runtime.h>
#include <cstdint>

#define SRC_LEN 2048
#define BSZ     64
#define CTX     512
#define ATT     256
#define BM      128
#define BK      32
#define NT      16          // K tiles = CTX/BK
#define NCHUNK  16
#define LOG2E   1.4426950408889634f
#define TILE_B  16384       // bytes per B tile (256 rows x 32 cols bf16)

typedef unsigned short u16;
typedef unsigned int   u32;
typedef unsigned char  u8;
typedef __attribute__((ext_vector_type(8))) short bf16x8;
typedef __attribute__((ext_vector_type(4))) float f32x4;

__device__ __forceinline__ u16 f2bf(float f) {
    u32 u = __float_as_uint(f);
    u32 r = (u + 0x7FFFu + ((u >> 16) & 1u)) >> 16;
    return (u16)r;
}
__device__ __forceinline__ float bf2f(u16 h) { return __uint_as_float((u32)h << 16); }

__device__ __forceinline__ float fast_exp2(float x) {
#if __has_builtin(__builtin_amdgcn_exp2f)
    return __builtin_amdgcn_exp2f(x);
#else
    return exp2f(x);
#endif
}
__device__ __forceinline__ float fast_rcp(float x) {
#if __has_builtin(__builtin_amdgcn_rcpf)
    return __builtin_amdgcn_rcpf(x);
#else
    return 1.0f / x;
#endif
}
__device__ __forceinline__ float fast_tanh(float x) {
    float e = fast_exp2(x * (2.0f * LOG2E));
    return 1.0f - 2.0f * fast_rcp(e + 1.0f);
}

// async global->LDS, 16B per lane; LDS dest = uniform base + lane*16
typedef const __attribute__((address_space(1))) unsigned char ga_u8;
typedef __attribute__((address_space(3))) unsigned char ls_u8;
__device__ __forceinline__ void gl_lds16(const void* g, void* l) {
    __builtin_amdgcn_global_load_lds((ga_u8*)g, (ls_u8*)l, 16, 0, 0);
}

__device__ __forceinline__ int rowswz(int r) { return (r & 3) ^ ((r >> 2) & 3); }

// ---------------------------------------------------------------------------
// Kernel 1: prep — decoder projection; W_enc hi/lo split written PRE-SWIZZLED
// in per-K-tile layout so score's global_load_lds lands it ready; mask probe.
// grid 64, 256 threads
// ---------------------------------------------------------------------------
__global__ __launch_bounds__(256) void prep_kernel(
    const float* __restrict__ dec_state, const float* __restrict__ W_dec,
    const float* __restrict__ W_enc, const u8* __restrict__ mask_bytes,
    float* __restrict__ decproj, u16* __restrict__ whsw, u16* __restrict__ wlsw,
    int* __restrict__ flag)
{
    const int b = blockIdx.x, t = threadIdx.x;
    __shared__ float ds[CTX];
    for (int k = t; k < CTX; k += 256) ds[k] = dec_state[b * CTX + k];
    __syncthreads();

    // decproj[b][t] = dot(dec_state[b,:], W_dec[t,:])
    const float* wrow = W_dec + t * CTX;
    float acc = 0.f;
#pragma unroll 4
    for (int k = 0; k < CTX; k += 4) {
        float4 w4 = *reinterpret_cast<const float4*>(wrow + k);
        acc += w4.x * ds[k] + w4.y * ds[k + 1] + w4.z * ds[k + 2] + w4.w * ds[k + 3];
    }
    decproj[b * ATT + t] = acc;

    // W_enc split: one 16B chunk (8 elems) per thread, swizzled per-tile layout
    const int gid = b * 256 + t;          // 0..16383
    const int row = gid >> 6;             // 0..255
    const int rem = gid & 63;
    const int kt  = rem >> 2;             // 0..15
    const int c   = rem & 3;              // 0..3 (16B chunk within 32-col row)
    const float* src = W_enc + row * CTX + kt * BK + c * 8;
    float4 f0 = reinterpret_cast<const float4*>(src)[0];
    float4 f1 = reinterpret_cast<const float4*>(src)[1];
    float fv[8] = {f0.x, f0.y, f0.z, f0.w, f1.x, f1.y, f1.z, f1.w};
    u32 hp[4], lp[4];
#pragma unroll
    for (int j = 0; j < 4; ++j) {
        u16 h0 = f2bf(fv[2 * j]), h1 = f2bf(fv[2 * j + 1]);
        u16 l0 = f2bf(fv[2 * j] - bf2f(h0));
        u16 l1 = f2bf(fv[2 * j + 1] - bf2f(h1));
        hp[j] = (u32)h0 | ((u32)h1 << 16);
        lp[j] = (u32)l0 | ((u32)l1 << 16);
    }
    const int dst = kt * TILE_B + row * 64 + ((c ^ rowswz(row)) * 16);  // bytes
    uint4 uh = {hp[0], hp[1], hp[2], hp[3]};
    uint4 ul = {lp[0], lp[1], lp[2], lp[3]};
    *reinterpret_cast<uint4*>((char*)whsw + dst) = uh;
    *reinterpret_cast<uint4*>((char*)wlsw + dst) = ul;

    // mask dtype probe (int32 0/1 has zero bytes at idx%4!=0)
    int bad = 0;
#pragma unroll
    for (int i = 0; i < 8; ++i) {
        int idx = gid * 8 + i;
        if ((idx & 3) != 0 && mask_bytes[idx] != 0) bad = 1;
    }
    if (bad) atomicOr(flag, 1);
}

// ---------------------------------------------------------------------------
// Kernel 2: score — 2-term split-bf16 MFMA GEMM, prefetched 2-phase pipeline.
// A (hids fp32) -> regs (1 tile ahead) -> cvt hi-bf16 -> swizzled LDS.
// B (pre-split, pre-swizzled) -> global_load_lds (1 tile ahead, dbuf).
// grid 1024, 256 threads = 4 waves (wave n owns 64 output cols)
// ---------------------------------------------------------------------------
__global__ __launch_bounds__(256) void score_kernel(
    const float* __restrict__ hids, const u16* __restrict__ whsw,
    const u16* __restrict__ wlsw, const float* __restrict__ decproj,
    const float* __restrict__ b_enc, const float* __restrict__ vvec,
    const u8* __restrict__ maskB, const int* __restrict__ maskI,
    const int* __restrict__ flag, float* __restrict__ scoresT)
{
    __shared__ __align__(16) char smem[81920];   // A: 2x8KB | B: 2x32KB (hi+lo)

    const int tid  = threadIdx.x;
    const int wave = tid >> 6, lane = tid & 63;
    const int ln15 = lane & 15, lg = lane >> 4;
    const int rowBase = blockIdx.x * BM;
    const int arow = tid >> 1;          // 0..127
    const int half = tid & 1;
    const int asw  = rowswz(arow);

    f32x4 acc[8][4];
#pragma unroll
    for (int m = 0; m < 8; ++m)
#pragma unroll
        for (int n = 0; n < 4; ++n) acc[m][n] = (f32x4){0.f, 0.f, 0.f, 0.f};

    // ---- staging helpers ----
    auto stageB = [&](int t, int buf) {
        const char* gh = (const char*)whsw + t * TILE_B + wave * 4096 + lane * 16;
        const char* gl = (const char*)wlsw + t * TILE_B + wave * 4096 + lane * 16;
        char* lb = smem + 16384 + buf * 32768 + wave * 4096;
#pragma unroll
        for (int i = 0; i < 4; ++i) {
            gl_lds16(gh + i * 1024, lb + i * 1024);
            gl_lds16(gl + i * 1024, lb + 16384 + i * 1024);
        }
    };
    auto loadA = [&](int t, float4* ar) {
        const float* s = hids + (size_t)(rowBase + arow) * CTX + t * BK + half * 16;
#pragma unroll
        for (int q = 0; q < 4; ++q) ar[q] = reinterpret_cast<const float4*>(s)[q];
    };
    auto writeA = [&](const float4* ar, int buf) {
        u32 hp[8];
#pragma unroll
        for (int q = 0; q < 4; ++q) {
            u16 h0 = f2bf(ar[q].x), h1 = f2bf(ar[q].y);
            u16 h2 = f2bf(ar[q].z), h3 = f2bf(ar[q].w);
            hp[q * 2]     = (u32)h0 | ((u32)h1 << 16);
            hp[q * 2 + 1] = (u32)h2 | ((u32)h3 << 16);
        }
        char* base = smem + buf * 8192 + arow * 64;
        const int c0 = half * 2;
        uint4 u0 = {hp[0], hp[1], hp[2], hp[3]};
        uint4 u1 = {hp[4], hp[5], hp[6], hp[7]};
        *reinterpret_cast<uint4*>(base + ((c0 ^ asw) * 16)) = u0;
        *reinterpret_cast<uint4*>(base + (((c0 + 1) ^ asw) * 16)) = u1;
    };

    // ---- prologue: tile 0 staged, tile 1 A-loads in flight ----
    float4 ar[4];
    stageB(0, 0);
    loadA(0, ar);
    writeA(ar, 0);
    loadA(1, ar);
    __syncthreads();

    // ---- main loop ----
#pragma unroll 1
    for (int t = 0; t < NT; ++t) {
        const int cur = t & 1;
        if (t < NT - 1) stageB(t + 1, cur ^ 1);

        const u16* lBh = (const u16*)(smem + 16384 + cur * 32768);
        const u16* lBl = lBh + 8192;
        bf16x8 bH[4], bL[4];
#pragma unroll
        for (int n = 0; n < 4; ++n) {
            const int row = wave * 64 + n * 16 + ln15;
            const int off = row * 32 + ((lg ^ rowswz(row)) * 8);
            bH[n] = *reinterpret_cast<const bf16x8*>(lBh + off);
            bL[n] = *reinterpret_cast<const bf16x8*>(lBl + off);
        }
        const u16* lA = (const u16*)(smem + cur * 8192);
#pragma unroll
        for (int m = 0; m < 8; ++m) {
            const int row = m * 16 + ln15;
            const int off = row * 32 + ((lg ^ rowswz(row)) * 8);
            bf16x8 aH = *reinterpret_cast<const bf16x8*>(lA + off);
#pragma unroll
            for (int n = 0; n < 4; ++n) {
                acc[m][n] = __builtin_amdgcn_mfma_f32_16x16x32_bf16(aH, bH[n], acc[m][n], 0, 0, 0);
                acc[m][n] = __builtin_amdgcn_mfma_f32_16x16x32_bf16(aH, bL[n], acc[m][n], 0, 0, 0);
            }
        }
        if (t < NT - 1) {
            writeA(ar, cur ^ 1);              // consume tile t+1 regs (loads long in flight)
            if (t < NT - 2) loadA(t + 2, ar); // issue tile t+2
        }
        __syncthreads();
    }

    // ---- epilogue: x = enc + b_enc + decproj; score = sum tanh(x)*v ----
    float* spart = (float*)smem;   // [4][128], aliases staging LDS (loop barrier done)
    float bE[4], vE[4];
#pragma unroll
    for (int n = 0; n < 4; ++n) {
        const int a = wave * 64 + n * 16 + ln15;
        bE[n] = b_enc[a];
        vE[n] = vvec[a];
    }
#pragma unroll
    for (int m = 0; m < 8; ++m) {
#pragma unroll
        for (int j = 0; j < 4; ++j) {
            const int rl = m * 16 + lg * 4 + j;
            const int b  = rl & 63;
            const float* dp = decproj + b * ATT + wave * 64 + ln15;
            float partial = 0.f;
#pragma unroll
            for (int n = 0; n < 4; ++n) {
                float x = acc[m][n][j] + bE[n] + dp[n * 16];
                partial += fast_tanh(x) * vE[n];
            }
            partial += __shfl_xor(partial, 1);
            partial += __shfl_xor(partial, 2);
            partial += __shfl_xor(partial, 4);
            partial += __shfl_xor(partial, 8);
            if (ln15 == 0) spart[wave * BM + rl] = partial;
        }
    }
    __syncthreads();

    if (tid < BM) {
        const int rl = tid;
        const int s = (rowBase + rl) >> 6;
        const int b = rl & 63;
        float sc = spart[0 * BM + rl] + spart[1 * BM + rl] +
                   spart[2 * BM + rl] + spart[3 * BM + rl];
        const int isByte = *flag;
        int mv;
        if (isByte) mv = (int)maskB[s * BSZ + b];
        else        mv = maskI[s * BSZ + b];
        scoresT[b * SRC_LEN + s] = (mv != 0) ? -1e30f : sc;
    }
}

// ---------------------------------------------------------------------------
// Kernel 3: softmax over s per batch column b. grid 64, 256 threads.
// ---------------------------------------------------------------------------
__global__ __launch_bounds__(256) void softmax_kernel(
    const float* __restrict__ scoresT, float* __restrict__ wT,
    float* __restrict__ outNorm)
{
    const int b = blockIdx.x, t = threadIdx.x;
    const int wv = t >> 6, ln = t & 63;
    __shared__ float red[8];

    float v[8];
    float m = -1e30f;
#pragma unroll
    for (int i = 0; i < 8; ++i) {
        v[i] = scoresT[b * SRC_LEN + i * 256 + t];
        m = fmaxf(m, v[i]);
    }
#pragma unroll
    for (int o = 1; o < 64; o <<= 1) m = fmaxf(m, __shfl_xor(m, o));
    if (ln == 0) red[wv] = m;
    __syncthreads();
    m = fmaxf(fmaxf(red[0], red[1]), fmaxf(red[2], red[3]));

    float e[8];
    float ssum = 0.f;
#pragma unroll
    for (int i = 0; i < 8; ++i) {
        e[i] = fast_exp2((v[i] - m) * LOG2E);
        ssum += e[i];
    }
#pragma unroll
    for (int o = 1; o < 64; o <<= 1) ssum += __shfl_xor(ssum, o);
    if (ln == 0) red[4 + wv] = ssum;
    __syncthreads();
    ssum = red[4] + red[5] + red[6] + red[7];

    const float inv = 1.0f / ssum;
#pragma unroll
    for (int i = 0; i < 8; ++i) {
        const float w = e[i] * inv;
        const int s = i * 256 + t;
        wT[b * SRC_LEN + s] = w;
        outNorm[s * BSZ + b] = w;
    }
}

// ---------------------------------------------------------------------------
// Kernel 4: context partial sums. grid (64 b, 16 s-chunks), 128 threads.
// ---------------------------------------------------------------------------
__global__ __launch_bounds__(128) void context_partial(
    const float* __restrict__ hids, const float* __restrict__ wT,
    float* __restrict__ partials)
{
    const int b = blockIdx.x, chunk = blockIdx.y, t = threadIdx.x;
    float4 acc = {0.f, 0.f, 0.f, 0.f};
    const int s0 = chunk * (SRC_LEN / NCHUNK);
#pragma unroll 4
    for (int s = s0; s < s0 + (SRC_LEN / NCHUNK); ++s) {
        const float w = wT[b * SRC_LEN + s];
        if (w != 0.0f) {
            float4 h = reinterpret_cast<const float4*>(hids + (size_t)(s * BSZ + b) * CTX)[t];
            acc.x += w * h.x; acc.y += w * h.y; acc.z += w * h.z; acc.w += w * h.w;
        }
    }
    reinterpret_cast<float4*>(partials + (size_t)(chunk * BSZ + b) * CTX)[t] = acc;
}

// ---------------------------------------------------------------------------
// Kernel 5: reduce partials -> context output. grid 64, 128 threads.
// ---------------------------------------------------------------------------
__global__ __launch_bounds__(128) void context_reduce(
    const float* __restrict__ partials, float* __restrict__ ctx)
{
    const int b = blockIdx.x, t = threadIdx.x;
    float4 acc = {0.f, 0.f, 0.f, 0.f};
#pragma unroll
    for (int c = 0; c < NCHUNK; ++c) {
        float4 p = reinterpret_cast<const float4*>(partials + (size_t)(c * BSZ + b) * CTX)[t];
        acc.x += p.x; acc.y += p.y; acc.z += p.z; acc.w += p.w;
    }
    reinterpret_cast<float4*>(ctx + (size_t)b * CTX)[t] = acc;
}

// ---------------------------------------------------------------------------
extern "C" void kernel_launch(void* const* d_in, const int* in_sizes, int n_in,
                              void* d_out, int out_size, void* d_ws, size_t ws_size,
                              hipStream_t stream)
{
    const float* dec_state = (const float*)d_in[0];
    const float* hids      = (const float*)d_in[1];
    const void*  mask_raw  = d_in[2];
    const float* W_enc     = (const float*)d_in[3];
    const float* b_enc     = (const float*)d_in[4];
    const float* W_dec     = (const float*)d_in[5];
    const float* vvec      = (const float*)d_in[6];

    float* out_ctx  = (float*)d_out;                 // [64][512]
    float* out_norm = out_ctx + BSZ * CTX;           // [2048][64]

    char* ws = (char*)d_ws;
    float* decproj  = (float*)(ws);                  //  64*256*4   = 65536
    u16*   whsw     = (u16*)(ws + 65536);            // 16 tiles * 16384 B = 262144
    u16*   wlsw     = (u16*)(ws + 65536 + 262144);   // 262144
    float* scoresT  = (float*)(ws + 589824);         // 64*2048*4   = 524288
    float* wT       = (float*)(ws + 1114112);        // 524288
    float* partials = (float*)(ws + 1638400);        // 16*64*512*4 = 2097152
    int*   flag     = (int*)(ws + 3735552);

    hipMemsetAsync(flag, 0, 4, stream);

    prep_kernel<<<64, 256, 0, stream>>>(dec_state, W_dec, W_enc,
                                        (const u8*)mask_raw, decproj, whsw, wlsw, flag);

    score_kernel<<<(SRC_LEN * BSZ) / BM, 256, 0, stream>>>(
        hids, whsw, wlsw, decproj, b_enc, vvec,
        (const u8*)mask_raw, (const int*)mask_raw, flag, scoresT);

    softmax_kernel<<<BSZ, 256, 0, stream>>>(scoresT, wT, out_norm);

    context_partial<<<dim3(BSZ, NCHUNK), 128, 0, stream>>>(hids, wT, partials);

    context_reduce<<<BSZ, 128, 0, stream>>>(partials, out_ctx);
}